// Round 1
// baseline (1143.659 us; speedup 1.0000x reference)
//
#include <hip/hip_runtime.h>

// Problem constants
#define BB 64
#define UU 1024
#define HH 16
#define MM 512
#define DD 4
#define NR 8208   // H*(M+1)
#define NW 8192   // H*M
#define NK 1024   // U

// ---------------------------------------------------------------------------
// small helpers
// ---------------------------------------------------------------------------
__device__ inline float warp_reduce_max(float v) {
    #pragma unroll
    for (int off = 32; off > 0; off >>= 1) v = fmaxf(v, __shfl_xor(v, off));
    return v;
}
__device__ inline float warp_reduce_sum(float v) {
    #pragma unroll
    for (int off = 32; off > 0; off >>= 1) v += __shfl_xor(v, off);
    return v;
}

__global__ void k_zero(float* __restrict__ p) {
    p[blockIdx.x * 256 + threadIdx.x] = 0.0f;
}

// memsum[b,u] += sum_m mem[b,m,u]   grid (B, 16), block 256 (each thread 4 u's)
__global__ __launch_bounds__(256) void k_memsum(const float* __restrict__ mem,
                                                float* __restrict__ memsum) {
    const int b = blockIdx.x, mc = blockIdx.y, t = threadIdx.x;
    const float4* src = (const float4*)(mem + (size_t)b * MM * UU);
    float4 s = make_float4(0.f, 0.f, 0.f, 0.f);
    const int m0 = mc * 32;
    for (int m = m0; m < m0 + 32; ++m) {
        float4 v = src[(size_t)m * 256 + t];
        s.x += v.x; s.y += v.y; s.z += v.z; s.w += v.w;
    }
    float* d = memsum + b * UU + t * 4;
    atomicAdd(d + 0, s.x); atomicAdd(d + 1, s.y);
    atomicAdd(d + 2, s.z); atomicAdd(d + 3, s.w);
}

// memstate = (memsum + out)/513 ; wsum = 0    grid 256, block 256
__global__ void k_prep_r(const float* __restrict__ memsum, const float* __restrict__ out,
                         float* __restrict__ memstate, float* __restrict__ wsum) {
    int i = blockIdx.x * 256 + threadIdx.x;
    memstate[i] = (memsum[i] + out[i]) * (1.0f / 513.0f);
    wsum[i] = 0.0f;
}

// ---------------------------------------------------------------------------
// Skinny GEMM: C[64,N] partial = A[64, kbase:kbase+kchunk] @ W[kbase:.., N]
// block = 256 threads (4 waves); block tile = 64 rows x 128 cols
// wave w: rows w*16..w*16+15, lane: 2 consecutive cols. K-split over blockIdx.y,
// partials written to pbuf[ks][64][N] (summed by the consumer kernel).
// ---------------------------------------------------------------------------
__global__ __launch_bounds__(256) void k_gemm(const float* __restrict__ A,
                                              const float* __restrict__ W,
                                              float* __restrict__ pbuf,
                                              int N, int kchunk, int kcl2 /*log2(kchunk/4)*/) {
    __shared__ float At[256 * 64];   // At[kk][r], 64 KB max
    const int t = threadIdx.x;
    const int cb = blockIdx.x * 128;
    const int ks = blockIdx.y;
    const int kbase = ks * kchunk;

    // stage A[64][kchunk] transposed into LDS
    const int n4 = kchunk >> 4;              // float4 loads per thread
    const int kq_mask = (kchunk >> 2) - 1;
    for (int i = 0; i < n4; ++i) {
        int idx4 = t + (i << 8);
        int r = idx4 >> kcl2;
        int kq = idx4 & kq_mask;
        float4 v = *(const float4*)(A + r * UU + kbase + (kq << 2));
        int kk = kq << 2;
        At[(kk + 0) * 64 + r] = v.x;
        At[(kk + 1) * 64 + r] = v.y;
        At[(kk + 2) * 64 + r] = v.z;
        At[(kk + 3) * 64 + r] = v.w;
    }
    __syncthreads();

    const int wave = t >> 6;
    const int lane = t & 63;
    const int row0 = wave << 4;
    const int col = cb + (lane << 1);
    const bool wvalid = (col + 2 <= N);
    const float* Wp = W + (size_t)kbase * N + col;

    float acc[16][2];
    #pragma unroll
    for (int r = 0; r < 16; ++r) { acc[r][0] = 0.f; acc[r][1] = 0.f; }

    float2 wb0[8], wb1[8];
    if (wvalid) {
        #pragma unroll
        for (int i = 0; i < 8; ++i) wb0[i] = *(const float2*)(Wp + (size_t)i * N);
    }
    for (int kb = 0; kb < kchunk; kb += 8) {
        if (wvalid && (kb + 8 < kchunk)) {
            #pragma unroll
            for (int i = 0; i < 8; ++i)
                wb1[i] = *(const float2*)(Wp + (size_t)(kb + 8 + i) * N);
        }
        #pragma unroll
        for (int i = 0; i < 8; ++i) {
            const float* ap = &At[(kb + i) * 64 + row0];
            float a[16];
            *(float4*)&a[0]  = *(const float4*)(ap + 0);
            *(float4*)&a[4]  = *(const float4*)(ap + 4);
            *(float4*)&a[8]  = *(const float4*)(ap + 8);
            *(float4*)&a[12] = *(const float4*)(ap + 12);
            float2 wv = wb0[i];
            #pragma unroll
            for (int r = 0; r < 16; ++r) {
                acc[r][0] = fmaf(a[r], wv.x, acc[r][0]);
                acc[r][1] = fmaf(a[r], wv.y, acc[r][1]);
            }
        }
        #pragma unroll
        for (int i = 0; i < 8; ++i) wb0[i] = wb1[i];
    }

    if (wvalid) {
        float* dst = pbuf + (size_t)ks * 64 * N + col;
        #pragma unroll
        for (int r = 0; r < 16; ++r) {
            float2 o; o.x = acc[r][0]; o.y = acc[r][1];
            *(float2*)(dst + (size_t)(row0 + r) * N) = o;
        }
    }
}

// Softmax over slots per (b,h). Reads K-split partials + bias, writes outT[b][h][slot].
// grid B*H, block 256. S = number of slots (513 or 512), logit col j = slot*H + h.
__global__ __launch_bounds__(256) void k_softmax(const float* __restrict__ pbuf,
                                                 const float* __restrict__ bias,
                                                 float* __restrict__ outT,
                                                 int N, int S, int ksplit) {
    __shared__ float sm[4];
    const int b = blockIdx.x >> 4;
    const int h = blockIdx.x & 15;
    const int t = threadIdx.x;

    float v[3];
    float mx = -1e30f;
    #pragma unroll
    for (int i = 0; i < 3; ++i) {
        int slot = t + (i << 8);
        float val = -1e30f;
        if (slot < S) {
            int j = slot * HH + h;
            val = bias[j];
            for (int ks = 0; ks < ksplit; ++ks)
                val += pbuf[(size_t)(ks * BB + b) * N + j];
        }
        v[i] = val;
        mx = fmaxf(mx, val);
    }
    mx = warp_reduce_max(mx);
    if ((t & 63) == 0) sm[t >> 6] = mx;
    __syncthreads();
    mx = fmaxf(fmaxf(sm[0], sm[1]), fmaxf(sm[2], sm[3]));
    __syncthreads();

    float sum = 0.f;
    #pragma unroll
    for (int i = 0; i < 3; ++i) {
        int slot = t + (i << 8);
        if (slot < S) { v[i] = __expf(v[i] - mx); sum += v[i]; }
    }
    sum = warp_reduce_sum(sum);
    if ((t & 63) == 0) sm[t >> 6] = sum;
    __syncthreads();
    sum = sm[0] + sm[1] + sm[2] + sm[3];
    const float inv = 1.0f / sum;
    #pragma unroll
    for (int i = 0; i < 3; ++i) {
        int slot = t + (i << 8);
        if (slot < S) outT[(size_t)(b * HH + h) * S + slot] = v[i] * inv;
    }
}

// wsum[b,u] += sum_m rw[b,h(u),m] * mem[b,m,u]   grid (B,16), block 256 x 4u
__global__ __launch_bounds__(256) void k_passA(const float* __restrict__ mem,
                                               const float* __restrict__ rwT,
                                               float* __restrict__ wsum) {
    const int b = blockIdx.x, mc = blockIdx.y, t = threadIdx.x;
    const int h = t >> 4;   // u = 4t, h = u/64
    const float4* src = (const float4*)(mem + (size_t)b * MM * UU);
    const float* rw = rwT + (size_t)(b * HH + h) * (MM + 1);
    float4 s = make_float4(0.f, 0.f, 0.f, 0.f);
    const int m0 = mc * 32;
    for (int m = m0; m < m0 + 32; ++m) {
        float wgt = rw[m];
        float4 v = src[(size_t)m * 256 + t];
        s.x = fmaf(wgt, v.x, s.x); s.y = fmaf(wgt, v.y, s.y);
        s.z = fmaf(wgt, v.z, s.z); s.w = fmaf(wgt, v.w, s.w);
    }
    float* d = wsum + b * UU + t * 4;
    atomicAdd(d + 0, s.x); atomicAdd(d + 1, s.y);
    atomicAdd(d + 2, s.z); atomicAdd(d + 3, s.w);
}

// kin = wsum + out * rw[b,h,slot=M]  (the input-slot read-attention term)
__global__ void k_prep_k(const float* __restrict__ wsum, const float* __restrict__ out,
                         const float* __restrict__ rwT, float* __restrict__ kin) {
    int i = blockIdx.x * 256 + threadIdx.x;
    int b = i >> 10, u = i & 1023;
    int h = u >> 6;
    float r = rwT[(size_t)(b * HH + h) * (MM + 1) + MM];
    kin[i] = fmaf(out[i], r, wsum[i]);
}

// newval = relu(sum_ks kpartials + bk); also zero memsum for the coming update pass;
// on the last layer also write the `out` output.
__global__ void k_relu(const float* __restrict__ pbuf, const float* __restrict__ bk,
                       float* __restrict__ newval, float* __restrict__ memsum,
                       float* __restrict__ outdst) {
    int i = blockIdx.x * 256 + threadIdx.x;
    int b = i >> 10, u = i & 1023;
    float v = bk[u];
    for (int ks = 0; ks < 32; ++ks) v += pbuf[(size_t)(ks * BB + b) * NK + u];
    v = fmaxf(v, 0.f);
    newval[i] = v;
    memsum[i] = 0.f;
    if (outdst) outdst[i] = v;
}

// mem_new = (1-ww)*mem + ww*newval ; optionally accumulate memsum for next layer.
// grid (B,16), block 256 x 4u. In-place safe (elementwise).
__global__ __launch_bounds__(256) void k_update(const float* __restrict__ src,
                                                float* __restrict__ dst,
                                                const float* __restrict__ wwT,
                                                const float* __restrict__ newval,
                                                float* __restrict__ memsum, int do_sum) {
    const int b = blockIdx.x, mc = blockIdx.y, t = threadIdx.x;
    const int h = t >> 4;
    const float4* s4 = (const float4*)(src + (size_t)b * MM * UU);
    float4* d4 = (float4*)(dst + (size_t)b * MM * UU);
    const float* ww = wwT + (size_t)(b * HH + h) * MM;
    float4 nv = *(const float4*)(newval + b * UU + t * 4);
    float4 acc = make_float4(0.f, 0.f, 0.f, 0.f);
    const int m0 = mc * 32;
    for (int m = m0; m < m0 + 32; ++m) {
        float wgt = ww[m];
        float4 v = s4[(size_t)m * 256 + t];
        v.x = fmaf(wgt, nv.x - v.x, v.x);
        v.y = fmaf(wgt, nv.y - v.y, v.y);
        v.z = fmaf(wgt, nv.z - v.z, v.z);
        v.w = fmaf(wgt, nv.w - v.w, v.w);
        d4[(size_t)m * 256 + t] = v;
        acc.x += v.x; acc.y += v.y; acc.z += v.z; acc.w += v.w;
    }
    if (do_sum) {
        float* d = memsum + b * UU + t * 4;
        atomicAdd(d + 0, acc.x); atomicAdd(d + 1, acc.y);
        atomicAdd(d + 2, acc.z); atomicAdd(d + 3, acc.w);
    }
}

// ---------------------------------------------------------------------------
extern "C" void kernel_launch(void* const* d_in, const int* in_sizes, int n_in,
                              void* d_out, int out_size, void* d_ws, size_t ws_size,
                              hipStream_t stream) {
    const float* x    = (const float*)d_in[0];
    const float* memI = (const float*)d_in[1];
    const float* Wr   = (const float*)d_in[2];
    const float* br   = (const float*)d_in[3];
    const float* Ww   = (const float*)d_in[4];
    const float* bw   = (const float*)d_in[5];
    const float* Wk   = (const float*)d_in[6];
    const float* bk   = (const float*)d_in[7];

    float* outp   = (float*)d_out;        // [B,U]
    float* memOut = outp + BB * UU;       // [B,M,U] — also the working memory buffer

    // workspace layout (~14.2 MB)
    char* w = (char*)d_ws;
    float* pbuf     = (float*)(w + 0);          // 8,404,992 B (max 4x64x8208 f32)
    float* rwT      = (float*)(w + 8404992);    // [B][H][513]
    float* wwT      = (float*)(w + 10506240);   // [B][H][512]
    float* memsum   = (float*)(w + 12603392);   // [B,U]
    float* wsum     = (float*)(w + 12865536);   // [B,U]
    float* memstate = (float*)(w + 13127680);   // [B,U]
    float* kin      = (float*)(w + 13389824);   // [B,U]
    float* nv0      = (float*)(w + 13651968);   // [B,U]
    float* nv1      = (float*)(w + 13914112);   // [B,U]

    k_zero<<<BB * UU / 256, 256, 0, stream>>>(memsum);
    k_memsum<<<dim3(BB, 16), 256, 0, stream>>>(memI, memsum);

    const float* curOut = x;
    const float* curMem = memI;
    for (int l = 0; l < DD; ++l) {
        float* nv = (l & 1) ? nv1 : nv0;
        k_prep_r<<<BB * UU / 256, 256, 0, stream>>>(memsum, curOut, memstate, wsum);
        // rlog = memstate @ Wr[l]  (N=8208, ksplit=4, kchunk=256)
        k_gemm<<<dim3(65, 4), 256, 0, stream>>>(memstate, Wr + (size_t)l * UU * NR, pbuf, NR, 256, 6);
        k_softmax<<<BB * HH, 256, 0, stream>>>(pbuf, br + (size_t)l * NR, rwT, NR, MM + 1, 4);
        k_passA<<<dim3(BB, 16), 256, 0, stream>>>(curMem, rwT, wsum);
        k_prep_k<<<BB * UU / 256, 256, 0, stream>>>(wsum, curOut, rwT, kin);
        // klog = kin @ Wk[l]  (N=1024, ksplit=32, kchunk=32)
        k_gemm<<<dim3(8, 32), 256, 0, stream>>>(kin, Wk + (size_t)l * UU * NK, pbuf, NK, 32, 3);
        k_relu<<<BB * UU / 256, 256, 0, stream>>>(pbuf, bk + (size_t)l * NK, nv, memsum,
                                                  (l == DD - 1) ? outp : (float*)nullptr);
        // wlog = newval @ Ww[l]  (N=8192, ksplit=4, kchunk=256)
        k_gemm<<<dim3(64, 4), 256, 0, stream>>>(nv, Ww + (size_t)l * UU * NW, pbuf, NW, 256, 6);
        k_softmax<<<BB * HH, 256, 0, stream>>>(pbuf, bw + (size_t)l * NW, wwT, NW, MM, 4);
        k_update<<<dim3(BB, 16), 256, 0, stream>>>(curMem, memOut, wwT, nv, memsum,
                                                   (l < DD - 1) ? 1 : 0);
        curMem = memOut;
        curOut = nv;
    }
}